// Round 9
// baseline (92.110 us; speedup 1.0000x reference)
//
#include <hip/hip_runtime.h>
#include <hip/hip_bf16.h>

typedef __attribute__((ext_vector_type(8))) short short8;
typedef __attribute__((ext_vector_type(16))) float f32x16;

__device__ __forceinline__ unsigned short bfbits(float f) {
  return __builtin_bit_cast(unsigned short, __float2bfloat16(f));
}

__device__ __forceinline__ short8 lds_read16(const short* p, int byteOff) {
  return *reinterpret_cast<const short8*>(reinterpret_cast<const char*>(p) + byteOff);
}

#define MFMA(a, b, c) __builtin_amdgcn_mfma_f32_32x32x16_bf16((a), (b), (c), 0, 0, 0)

// x:[524288][64] f32 (flat reinterpret of [B,E,S,D]; expert = row>>16)
// w1:[8][64][256] f32, w2:[8][256][64] f32, out same shape as x.
// Grid 512 x 256 threads. expert = blockIdx&7 (XCD-pinned), chunk =
// blockIdx>>3 owns 1024 rows; 4 waves x 4 pair-iters x 64 rows.
//
// History (measured): R7 staging unroll-2 killed the reg spill (FETCH
// 282->67 MB) -> 86.7 us. R8 depth-2 x-prefetch = NO change -> x latency
// already hidden; kernel is dependency-latency-bound at 2 waves/SIMD
// (MfmaUtil 12%, VALUBusy 23%, 65% idle-issue). Occupancy is hard-capped:
// LDS 64 KB -> 2 blocks/CU; VGPR ~200 -> 2 waves/SIMD. R9: two-m-tile ILP
// (R1 structure, spill-free): 2 independent h chains + 4 o chains; tile B's
// VALU pack/shuffle overlaps tile A's MFMA. Register prefetch dropped (R8
// proved it worthless) to keep peak ~196 regs.
__launch_bounds__(256)
__global__ void ffn_fused(const float* __restrict__ x,
                          const float* __restrict__ w1,
                          const float* __restrict__ w2,
                          float* __restrict__ out) {
  // W1^T: [f=256][d=64] bf16, row pitch 128 B, byte ^= (f&7)<<4
  // W2^T: [d=64][f=256] bf16, row pitch 512 B, byte ^= (d&31)<<4
  __shared__ short w1t[256 * 64];
  __shared__ short w2t[64 * 256];

  const int tid  = threadIdx.x;
  const int lane = tid & 63;
  const int wv   = tid >> 6;   // wave 0..3
  const int m    = lane & 31;
  const int g    = lane >> 5;

  const int e     = blockIdx.x & 7;   // expert -> XCD pinned (128 KB weights/XCD-L2)
  const int chunk = blockIdx.x >> 3;  // 0..63

  const float* W1 = w1 + e * (64 * 256);
  const float* W2 = w2 + e * (256 * 64);

  const long rowBase = (long)e * 65536 + (long)chunk * 1024 + wv * 256;

  // ---- stage W1^T (thread t owns column f=t; 16 d-quads) ----
  // unroll 2: bound in-flight staging loads (full unroll spilled ~64 dw/thread)
  {
    const int f   = tid;
    const int swz = (f & 7) << 4;
#pragma unroll 2
    for (int i = 0; i < 16; ++i) {
      float a0 = W1[(4 * i + 0) * 256 + f];
      float a1 = W1[(4 * i + 1) * 256 + f];
      float a2 = W1[(4 * i + 2) * 256 + f];
      float a3 = W1[(4 * i + 3) * 256 + f];
      unsigned lo = (unsigned)bfbits(a0) | ((unsigned)bfbits(a1) << 16);
      unsigned hi = (unsigned)bfbits(a2) | ((unsigned)bfbits(a3) << 16);
      const int off = (f * 128 + i * 8) ^ swz;
      *reinterpret_cast<uint2*>(reinterpret_cast<char*>(w1t) + off) = make_uint2(lo, hi);
    }
  }
  // ---- stage W2^T (thread t owns column d=t&63; 16 f-quads) ----
  {
    const int d   = tid & 63;
    const int fb  = tid >> 6;  // 0..3
    const int swz = (d & 31) << 4;
#pragma unroll 2
    for (int i = 0; i < 16; ++i) {
      const int f4 = fb + 4 * i;
      const int f  = 4 * f4;
      float a0 = W2[(f + 0) * 64 + d];
      float a1 = W2[(f + 1) * 64 + d];
      float a2 = W2[(f + 2) * 64 + d];
      float a3 = W2[(f + 3) * 64 + d];
      unsigned lo = (unsigned)bfbits(a0) | ((unsigned)bfbits(a1) << 16);
      unsigned hi = (unsigned)bfbits(a2) | ((unsigned)bfbits(a3) << 16);
      const int off = (d * 512 + f4 * 8) ^ swz;
      *reinterpret_cast<uint2*>(reinterpret_cast<char*>(w2t) + off) = make_uint2(lo, hi);
    }
  }
  __syncthreads();  // only barrier in the kernel

  const int swzm = (m & 7) << 4;
  const int swzd = m << 4;  // ((d&31)<<4, d = m and 32+m give same value)

  for (int it = 0; it < 4; ++it) {
    const long rb = rowBase + it * 64;  // this wave's 64 rows this pair

    // ---- load + convert both tiles' x fragments (no reg prefetch: R8
    //      proved load latency is hidden; saves 64 VGPRs for ILP) ----
    short8 xfA[4], xfB[4];
#pragma unroll
    for (int ks = 0; ks < 4; ++ks) {
      const float* pa = x + (rb + m) * 64 + ks * 16 + g * 8;
      const float4 a0 = *reinterpret_cast<const float4*>(pa);
      const float4 a1 = *reinterpret_cast<const float4*>(pa + 4);
      const float* pb = x + (rb + 32 + m) * 64 + ks * 16 + g * 8;
      const float4 b0 = *reinterpret_cast<const float4*>(pb);
      const float4 b1 = *reinterpret_cast<const float4*>(pb + 4);
      short8 va, vb;
      va[0] = (short)bfbits(a0.x); va[1] = (short)bfbits(a0.y);
      va[2] = (short)bfbits(a0.z); va[3] = (short)bfbits(a0.w);
      va[4] = (short)bfbits(a1.x); va[5] = (short)bfbits(a1.y);
      va[6] = (short)bfbits(a1.z); va[7] = (short)bfbits(a1.w);
      vb[0] = (short)bfbits(b0.x); vb[1] = (short)bfbits(b0.y);
      vb[2] = (short)bfbits(b0.z); vb[3] = (short)bfbits(b0.w);
      vb[4] = (short)bfbits(b1.x); vb[5] = (short)bfbits(b1.y);
      vb[6] = (short)bfbits(b1.z); vb[7] = (short)bfbits(b1.w);
      xfA[ks] = va;
      xfB[ks] = vb;
    }

    f32x16 o00, o01, o10, o11;  // o[dt][tile]
#pragma unroll
    for (int i = 0; i < 16; ++i) { o00[i] = 0.f; o01[i] = 0.f; o10[i] = 0.f; o11[i] = 0.f; }

#pragma unroll
    for (int ft = 0; ft < 8; ++ft) {
      // GEMM1: two independent h chains (tile A, tile B) share a-frags
      short8 a[4];
#pragma unroll
      for (int ks = 0; ks < 4; ++ks)
        a[ks] = lds_read16(w1t, ((ft * 32 + m) * 128 + ks * 32 + g * 16) ^ swzm);

      f32x16 h0, h1;
#pragma unroll
      for (int i = 0; i < 16; ++i) { h0[i] = 0.f; h1[i] = 0.f; }
#pragma unroll
      for (int ks = 0; ks < 4; ++ks) {
        h0 = MFMA(a[ks], xfA[ks], h0);
        h1 = MFMA(a[ks], xfB[ks], h1);
      }

      // relu + pack to bf16 pairs
      unsigned pk0[8], pk1[8];
#pragma unroll
      for (int q = 0; q < 4; ++q) {
        pk0[2*q]   = (unsigned)bfbits(fmaxf(h0[4*q+0], 0.f)) | ((unsigned)bfbits(fmaxf(h0[4*q+1], 0.f)) << 16);
        pk0[2*q+1] = (unsigned)bfbits(fmaxf(h0[4*q+2], 0.f)) | ((unsigned)bfbits(fmaxf(h0[4*q+3], 0.f)) << 16);
        pk1[2*q]   = (unsigned)bfbits(fmaxf(h1[4*q+0], 0.f)) | ((unsigned)bfbits(fmaxf(h1[4*q+1], 0.f)) << 16);
        pk1[2*q+1] = (unsigned)bfbits(fmaxf(h1[4*q+2], 0.f)) | ((unsigned)bfbits(fmaxf(h1[4*q+3], 0.f)) << 16);
      }

      // GEMM2: 4 independent o chains; h^T B-frags via proven shfl_xor net
#pragma unroll
      for (int sub = 0; sub < 2; ++sub) {
        const int ks2 = 2 * ft + sub;
        const short8 wA = lds_read16(w2t, (m * 512 + ks2 * 32 + g * 16) ^ swzd);
        const short8 wB = lds_read16(w2t, ((32 + m) * 512 + ks2 * 32 + g * 16) ^ swzd);
        const int qa = 2 * sub, qb = 2 * sub + 1;

        union { short8 v; unsigned u[4]; } b0, b1;
        {
          unsigned pa0 = pk0[2*qa], pa1 = pk0[2*qa+1];
          unsigned pb0 = pk0[2*qb], pb1 = pk0[2*qb+1];
          unsigned s0 = g ? pa0 : pb0, s1 = g ? pa1 : pb1;
          unsigned k0 = g ? pb0 : pa0, k1 = g ? pb1 : pa1;
          unsigned r0 = __shfl_xor(s0, 32, 64);
          unsigned r1 = __shfl_xor(s1, 32, 64);
          b0.u[0] = g ? r0 : k0; b0.u[1] = g ? r1 : k1;
          b0.u[2] = g ? k0 : r0; b0.u[3] = g ? k1 : r1;
        }
        {
          unsigned pa0 = pk1[2*qa], pa1 = pk1[2*qa+1];
          unsigned pb0 = pk1[2*qb], pb1 = pk1[2*qb+1];
          unsigned s0 = g ? pa0 : pb0, s1 = g ? pa1 : pb1;
          unsigned k0 = g ? pb0 : pa0, k1 = g ? pb1 : pa1;
          unsigned r0 = __shfl_xor(s0, 32, 64);
          unsigned r1 = __shfl_xor(s1, 32, 64);
          b1.u[0] = g ? r0 : k0; b1.u[1] = g ? r1 : k1;
          b1.u[2] = g ? k0 : r0; b1.u[3] = g ? k1 : r1;
        }

        o00 = MFMA(wA, b0.v, o00);
        o10 = MFMA(wB, b0.v, o10);
        o01 = MFMA(wA, b1.v, o01);
        o11 = MFMA(wB, b1.v, o11);
      }
    }

    // ---- store both tiles' out^T C-frags ----
#pragma unroll
    for (int mt = 0; mt < 2; ++mt) {
#pragma unroll
      for (int dt = 0; dt < 2; ++dt) {
        const f32x16& acc = (mt == 0) ? (dt == 0 ? o00 : o10) : (dt == 0 ? o01 : o11);
        float* po = out + (rb + mt * 32 + m) * 64 + dt * 32 + g * 4;
#pragma unroll
        for (int q = 0; q < 4; ++q) {
          float4 s;
          s.x = acc[4*q+0]; s.y = acc[4*q+1]; s.z = acc[4*q+2]; s.w = acc[4*q+3];
          *reinterpret_cast<float4*>(po + 8 * q) = s;
        }
      }
    }
  }
}

extern "C" void kernel_launch(void* const* d_in, const int* in_sizes, int n_in,
                              void* d_out, int out_size, void* d_ws, size_t ws_size,
                              hipStream_t stream) {
  const float* x  = (const float*)d_in[0];
  const float* w1 = (const float*)d_in[1];
  const float* w2 = (const float*)d_in[2];
  float* out = (float*)d_out;
  ffn_fused<<<dim3(512), dim3(256), 0, stream>>>(x, w1, w2, out);
}